// Round 8
// baseline (279.573 us; speedup 1.0000x reference)
//
#include <hip/hip_runtime.h>
#include <hip/hip_fp16.h>

// Fused MHA block: y = LN(x + b_proj + softmax(QK^T/8) V W_proj), MFMA compute.
// B=4, S=2048, D=1024, H=16, Dh=64.  M = B*S = 8192.
//
// Workspace layout (needs ~72 MB; aliased):
//   [0,16M)   x_bf16 [8192][1024]     -- later reused as O bf16 [8192][1024]
//   [16,22M)  wqkvT bf16 [3072n][1024k]  (wq/wk/wv transposed, contiguous)
//   [22,24M)  wprojT bf16 [1024n][1024k]
//   [24,40M)  Q bf16 [8192][1024]  (PRE-SCALED by 0.125*log2e; n = h*64+dh)
//   [40,56M)  K bf16
//   [56,72M)  V^T f16 [b][h][dh][s]   (written transposed+f16 by QKV GEMM epilogue)
//   [24,40M)  y_pre bf16 [8192][1024]  (aliases Q after attention)

typedef unsigned short u16;
typedef __attribute__((ext_vector_type(8))) u16 u16x8;
typedef __attribute__((ext_vector_type(4))) u16 u16x4;
typedef __attribute__((ext_vector_type(2))) unsigned int u32x2;
typedef __attribute__((ext_vector_type(8))) __bf16 bf16x8;
typedef __attribute__((ext_vector_type(8))) _Float16 f16x8;
typedef __attribute__((ext_vector_type(4))) _Float16 f16x4;
typedef __attribute__((ext_vector_type(2))) _Float16 f16x2;
typedef __attribute__((ext_vector_type(2))) __fp16 hf16x2;   // cvt_pkrtz return type
typedef __attribute__((ext_vector_type(4))) float f32x4;

#define SM_C1 0.1803368801111204f   /* 0.125 * log2(e) */

static __device__ __forceinline__ u16 f2bf(float f) {
  union { float f; unsigned int u; } v; v.f = f;
  unsigned int u = v.u;
  return (u16)((u + 0x7fffu + ((u >> 16) & 1u)) >> 16);  // RNE
}
static __device__ __forceinline__ float bf2f(u16 b) {
  union { unsigned int u; float f; } v; v.u = ((unsigned int)b) << 16;
  return v.f;
}
static __device__ __forceinline__ u16 f2h(float f) {
  union { _Float16 h; u16 u; } v; v.h = (_Float16)f;  // v_cvt_f16_f32, RNE
  return v.u;
}

// async global->LDS, 16B per lane; LDS dest = wave-uniform base + lane*16
static __device__ __forceinline__ void gld16(const u16* g, u16* l) {
  __builtin_amdgcn_global_load_lds((const __attribute__((address_space(1))) void*)g,
                                   (__attribute__((address_space(3))) void*)l, 16, 0, 0);
}

// raw barrier with compiler memory fences (no sched_barrier pinning)
#define QBAR() do { asm volatile("" ::: "memory"); __builtin_amdgcn_s_barrier(); \
                    asm volatile("" ::: "memory"); } while (0)
#define QDRAIN() asm volatile("s_waitcnt vmcnt(0)" ::: "memory")
#define QWAIT6() asm volatile("s_waitcnt vmcnt(6)" ::: "memory")

// ---------------- fused conversion kernel ----------------
// blocks [0,4096): x fp32 -> bf16 (vectorized)
// blocks [4096,5120): 4x 1024x1024 fp32 -> bf16 [n][k] transpose (LDS tiled)
// Merged so both co-schedule in one launch (one less gap; fills machine).

__global__ __launch_bounds__(256) void k_conv(const float* __restrict__ x,
                                              u16* __restrict__ xbf,
                                              const float* __restrict__ w0,
                                              const float* __restrict__ w1,
                                              const float* __restrict__ w2,
                                              const float* __restrict__ w3,
                                              u16* __restrict__ o0, u16* __restrict__ o1,
                                              u16* __restrict__ o2, u16* __restrict__ o3) {
  __shared__ float tile[64][65];
  const int t = threadIdx.x;
  if (blockIdx.x < 4096) {
    int i = (blockIdx.x * 256 + t) * 8;
    float4 a = *(const float4*)(x + i);
    float4 b = *(const float4*)(x + i + 4);
    u16x8 o;
    o[0] = f2bf(a.x); o[1] = f2bf(a.y); o[2] = f2bf(a.z); o[3] = f2bf(a.w);
    o[4] = f2bf(b.x); o[5] = f2bf(b.y); o[6] = f2bf(b.z); o[7] = f2bf(b.w);
    *(u16x8*)(xbf + i) = o;
    return;
  }
  const int id = blockIdx.x - 4096;          // 0..1023
  const int z = id >> 8, rem = id & 255;
  const int k0 = (rem & 15) * 64, n0 = (rem >> 4) * 64;
  const float* w = z == 0 ? w0 : z == 1 ? w1 : z == 2 ? w2 : w3;
  u16* o = z == 0 ? o0 : z == 1 ? o1 : z == 2 ? o2 : o3;
#pragma unroll
  for (int i = 0; i < 16; i++) {
    int idx = t + 256 * i;
    int k = idx >> 6, n = idx & 63;
    tile[k][n] = w[(k0 + k) * 1024 + n0 + n];
  }
  __syncthreads();
#pragma unroll
  for (int i = 0; i < 16; i++) {
    int idx = t + 256 * i;
    int n = idx >> 6, k = idx & 63;
    o[(n0 + n) * 1024 + k0 + k] = f2bf(tile[k][n]);
  }
}

// ---------------- QKV GEMM: 256x128 tile, counted-vmcnt double-buffer ----------------
// grid (32,24) = 768 blocks = exactly 3 waves of 256 CUs (zero tail), 96 KB LDS,
// 512 thr = 8 waves as 4Mx2N; per-wave tile 64x64 (acc[4][4], m97 frag pattern,
// same XOR-swizzled reads, bit-identical accumulation order).
// Per K-tile: { STAGE(t+1) issue; s_waitcnt vmcnt(6); barrier; ds_read frags;
// 32 MFMA; barrier }.  vmcnt(6) retires exactly tile t's 6 oldest loads
// (in-order retirement); NO vmcnt(0) in the loop.

__global__ __launch_bounds__(512, 2) void k_gemm_qkv(const u16* __restrict__ xbf,
                                                     const u16* __restrict__ wT,
                                                     u16* __restrict__ Qb, u16* __restrict__ Kb,
                                                     u16* __restrict__ VbT) {
  __shared__ alignas(16) u16 As[2][256 * 64];
  __shared__ alignas(16) u16 Bs[2][128 * 64];
  const int t = threadIdx.x;
  const int wv = t >> 6, lane = t & 63, quad = lane >> 4, l16 = lane & 15;
  const int wm = wv >> 1, wn = wv & 1;       // 4M x 2N wave grid
  const int m0 = blockIdx.x * 256;
  const int nt = blockIdx.y;                 // 0..23 (8 per matrix)
  const int srow = t >> 3;                   // staging row 0..63 (+64 per issue)
  const int kg = (t & 7) ^ (srow & 7);       // swizzled k-granule
  const u16* aG = xbf + (size_t)(m0 + srow) * 1024 + kg * 8;
  const u16* bG = wT + (size_t)(nt * 128 + srow) * 1024 + kg * 8;
  const int sw = l16 & 7;
  const int ldsDst = wv * 512;               // wave-uniform dest (u16 units) per issue

  f32x4 acc[4][4] = {};

  auto STAGE = [&](int tl) {
    const int p_ = tl & 1;
    const int k0_ = tl * 64;
#pragma unroll
    for (int i = 0; i < 4; i++)   // A: 256 rows, 64 per issue
      gld16(aG + (size_t)i * 64 * 1024 + k0_, &As[p_][i * 4096 + ldsDst]);
#pragma unroll
    for (int i = 0; i < 2; i++)   // B: 128 rows
      gld16(bG + (size_t)i * 64 * 1024 + k0_, &Bs[p_][i * 4096 + ldsDst]);
  };

  STAGE(0);

#pragma unroll 2
  for (int tile = 0; tile < 16; ++tile) {
    const int p = tile & 1;
    if (tile < 15) { STAGE(tile + 1); QWAIT6(); }
    else           { QDRAIN(); }
    QBAR();   // all waves' tile-t loads landed -> buf[p] fully populated

    bf16x8 a[4][2], b[4][2];
#pragma unroll
    for (int f = 0; f < 4; f++)
#pragma unroll
      for (int kk = 0; kk < 2; kk++)
        a[f][kk] = *(const bf16x8*)&As[p][(wm * 64 + f * 16 + l16) * 64 +
                                          ((kk * 4 + quad) ^ sw) * 8];
#pragma unroll
    for (int g = 0; g < 4; g++)
#pragma unroll
      for (int kk = 0; kk < 2; kk++)
        b[g][kk] = *(const bf16x8*)&Bs[p][(wn * 64 + g * 16 + l16) * 64 +
                                          ((kk * 4 + quad) ^ sw) * 8];
#pragma unroll
    for (int f = 0; f < 4; f++)
#pragma unroll
      for (int g = 0; g < 4; g++)
#pragma unroll
        for (int kk = 0; kk < 2; kk++)
          acc[f][g] = __builtin_amdgcn_mfma_f32_16x16x32_bf16(a[f][kk], b[g][kk], acc[f][g], 0, 0, 0);

    QBAR();   // reads of buf[p] done block-wide -> safe to recycle next iter
  }

  const int sel = nt >> 3;
  const int n0 = (nt & 7) * 128 + wn * 64;
  const int mBase = m0 + wm * 64 + quad * 4;
  if (sel < 2) {
    u16* Ob = sel == 0 ? Qb : Kb;
    const float scl = sel == 0 ? SM_C1 : 1.0f;
#pragma unroll
    for (int f = 0; f < 4; f++)
#pragma unroll
      for (int g = 0; g < 4; g++)
#pragma unroll
        for (int r = 0; r < 4; r++) {
          int m = mBase + f * 16 + r;
          int n = n0 + g * 16 + l16;
          Ob[(size_t)m * 1024 + n] = f2bf(acc[f][g][r] * scl);
        }
  } else {
    // V^T f16: [b][h][dh][s]; 4 r-values are 4 consecutive s -> one 8B store
#pragma unroll
    for (int f = 0; f < 4; f++) {
      int m = mBase + f * 16;
      int bb = m >> 11, s = m & 2047;
#pragma unroll
      for (int g = 0; g < 4; g++) {
        int n = n0 + g * 16 + l16;
        int hh = n >> 6, dh = n & 63;
        u16x4 o;
#pragma unroll
        for (int r = 0; r < 4; r++) o[r] = f2h(acc[f][g][r]);
        *(u16x4*)&VbT[(size_t)(((bb << 4) + hh) * 64 + dh) * 2048 + s] = o;
      }
    }
  }
}

// ---------------- proj GEMM: same 256x128 counted-vmcnt template ----------------
// grid (32,8) = 256 blocks = exactly 1 per CU (zero tail).  Epilogue: bias +
// fp32-x residual, bf16 y_pre out (identical math to the m97 version).

__global__ __launch_bounds__(512, 2) void k_gemm_proj(const u16* __restrict__ Abf,
                                                      const u16* __restrict__ wT,
                                                      const float* __restrict__ x,
                                                      const float* __restrict__ bias,
                                                      u16* __restrict__ ypre) {
  __shared__ alignas(16) u16 As[2][256 * 64];
  __shared__ alignas(16) u16 Bs[2][128 * 64];
  const int t = threadIdx.x;
  const int wv = t >> 6, lane = t & 63, quad = lane >> 4, l16 = lane & 15;
  const int wm = wv >> 1, wn = wv & 1;
  const int m0 = blockIdx.x * 256;
  const int n0t = blockIdx.y * 128;
  const int srow = t >> 3;
  const int kg = (t & 7) ^ (srow & 7);
  const u16* aG = Abf + (size_t)(m0 + srow) * 1024 + kg * 8;
  const u16* bG = wT + (size_t)(n0t + srow) * 1024 + kg * 8;
  const int sw = l16 & 7;
  const int ldsDst = wv * 512;

  f32x4 acc[4][4] = {};

  auto STAGE = [&](int tl) {
    const int p_ = tl & 1;
    const int k0_ = tl * 64;
#pragma unroll
    for (int i = 0; i < 4; i++)
      gld16(aG + (size_t)i * 64 * 1024 + k0_, &As[p_][i * 4096 + ldsDst]);
#pragma unroll
    for (int i = 0; i < 2; i++)
      gld16(bG + (size_t)i * 64 * 1024 + k0_, &Bs[p_][i * 4096 + ldsDst]);
  };

  STAGE(0);

#pragma unroll 2
  for (int tile = 0; tile < 16; ++tile) {
    const int p = tile & 1;
    if (tile < 15) { STAGE(tile + 1); QWAIT6(); }
    else           { QDRAIN(); }
    QBAR();

    bf16x8 a[4][2], b[4][2];
#pragma unroll
    for (int f = 0; f < 4; f++)
#pragma unroll
      for (int kk = 0; kk < 2; kk++)
        a[f][kk] = *(const bf16x8*)&As[p][(wm * 64 + f * 16 + l16) * 64 +
                                          ((kk * 4 + quad) ^ sw) * 8];
#pragma unroll
    for (int g = 0; g < 4; g++)
#pragma unroll
      for (int kk = 0; kk < 2; kk++)
        b[g][kk] = *(const bf16x8*)&Bs[p][(wn * 64 + g * 16 + l16) * 64 +
                                          ((kk * 4 + quad) ^ sw) * 8];
#pragma unroll
    for (int f = 0; f < 4; f++)
#pragma unroll
      for (int g = 0; g < 4; g++)
#pragma unroll
        for (int kk = 0; kk < 2; kk++)
          acc[f][g] = __builtin_amdgcn_mfma_f32_16x16x32_bf16(a[f][kk], b[g][kk], acc[f][g], 0, 0, 0);

    QBAR();
  }

  const int n0 = n0t + wn * 64;
  const int mBase = m0 + wm * 64 + quad * 4;
#pragma unroll
  for (int g = 0; g < 4; g++) {
    int n = n0 + g * 16 + l16;
    float bn = bias[n];
#pragma unroll
    for (int f = 0; f < 4; f++)
#pragma unroll
      for (int r = 0; r < 4; r++) {
        int m = mBase + f * 16 + r;
        ypre[(size_t)m * 1024 + n] = f2bf(acc[f][g][r] + bn + x[(size_t)m * 1024 + n]);
      }
  }
}

// ---------------- flash attention (transposed-score form, 128-q blocks) ----------------
// q-block 128 (grid (64,16) = 1024 blocks = 4 blocks/CU, launch_bounds(256,4)).
// r6 diagnosis: MfmaUtil 33 + VALUBusy 50, HBM 6%, Occupancy 17% = latency-bound
// on the exp dependent chain with only 2 waves/SIMD.  4 blocks/CU doubles
// resident waves (LDS 4x36.8KB = 147KB <= 160; VGPR ~90 <= 128).
// Per-wave work halves (qf=2); per-output arithmetic order IDENTICAL -> absmax
// canary must stay 0.03125.  K/V fetched per 128-q block (FETCH ~2x, still ~6%
// of HBM peak, XCD-local via grid (bh, qblk)).
// S^T = K Q_scaled^T (16x16x32 bf16); p~ = 2^s packed-f16 exp; PV full-rate
// 16x16x32 f16 with in-register C->B redistribution via permlane swaps.
// K/V staging via global_load_lds into linear [64][64] buffers, XOR-granule
// swizzle on the GLOBAL source address; frag reads swizzle by ^(l16&7)
// (bank conflicts measured 131K, was 6.4M).  No setprio (m190 null regime).

__global__ __launch_bounds__(256, 4) void k_attn(const u16* __restrict__ Qb,
                                                 const u16* __restrict__ Kb,
                                                 const u16* __restrict__ VbT,
                                                 u16* __restrict__ Ob) {
  // [0..1]: K ping/pong [64][64] bf16; [2..3]: V ping/pong [64][64] f16.
  // Regions padded to 64*72 so the O-epilogue transpose (128 rows x 72) fits.
  __shared__ alignas(16) u16 smem[4][64 * 72];
  const int b = blockIdx.x >> 4, h = blockIdx.x & 15;
  const int q0 = blockIdx.y * 128;
  const int t = threadIdx.x;
  const int wave = t >> 6, lane = t & 63, quad = lane >> 4, l16 = lane & 15;
  const int sw = l16 & 7;

  // Q fragments (pre-scaled); wave owns 32 q rows (2 q-frags)
  bf16x8 aq[2][2];
#pragma unroll
  for (int qf = 0; qf < 2; qf++)
#pragma unroll
    for (int c = 0; c < 2; c++)
      aq[qf][c] = *(const bf16x8*)&Qb[(size_t)(b * 2048 + q0 + wave * 32 + qf * 16 + l16) * 1024 +
                                      h * 64 + c * 32 + quad * 8];

  f32x4 Oacc[2][4] = {};   // [qf][dh-frag g]; C-layout col=q, row=dh_local
  float psum[2] = {};      // per-lane partial row sum for q=l16 (per qf)

  const u16* kBase = Kb + (size_t)(b * 2048) * 1024 + h * 64;
  const u16* vBase = VbT + (size_t)((b * 16 + h) * 64) * 2048;

  // staging: slot s = i*256 + t covers (row r = s>>3, granule gslot = s&7);
  // source granule = gslot ^ (r&7); LDS dest linear = s*16B (base wave-uniform).
  const int sRow0 = t >> 3, sG0 = (t & 7) ^ (sRow0 & 7);          // i=0
  const int sRow1 = (256 + t) >> 3, sG1 = (t & 7) ^ (sRow1 & 7);  // i=1

  auto STAGE = [&](int kt, int p) {
    const int kv = kt * 64;
    u16* Kls = smem[p];
    u16* Vls = smem[2 + p];
    gld16(kBase + (size_t)(kv + sRow0) * 1024 + sG0 * 8, &Kls[(wave * 64) * 8]);
    gld16(kBase + (size_t)(kv + sRow1) * 1024 + sG1 * 8, &Kls[(256 + wave * 64) * 8]);
    gld16(vBase + (size_t)sRow0 * 2048 + kv + sG0 * 8, &Vls[(wave * 64) * 8]);
    gld16(vBase + (size_t)sRow1 * 2048 + kv + sG1 * 8, &Vls[(256 + wave * 64) * 8]);
  };

  STAGE(0, 0);
  QDRAIN();
  QBAR();

  for (int kt = 0; kt < 32; kt++) {
    const int p = kt & 1;
    u16* Kls = smem[p];
    u16* Vls = smem[2 + p];
    if (kt < 31) STAGE(kt + 1, p ^ 1);   // flies across this iter's compute

    // S^T = K Q^T : A = K-frag (m=kv), B = Q-frag (n=q)
    f32x4 st[2][4];   // [qf][kv-frag f]
#pragma unroll
    for (int qf = 0; qf < 2; qf++)
#pragma unroll
      for (int f = 0; f < 4; f++) st[qf][f] = f32x4{0.f, 0.f, 0.f, 0.f};
#pragma unroll
    for (int c = 0; c < 2; c++) {
      bf16x8 bk[4];
#pragma unroll
      for (int f = 0; f < 4; f++)
        bk[f] = *(const bf16x8*)&Kls[(f * 16 + l16) * 64 + ((c * 4 + quad) ^ sw) * 8];
#pragma unroll
      for (int qf = 0; qf < 2; qf++)
#pragma unroll
        for (int f = 0; f < 4; f++)
          st[qf][f] = __builtin_amdgcn_mfma_f32_16x16x32_bf16(bk[f], aq[qf][c], st[qf][f], 0, 0, 0);
    }

    // V A-operand frags (K=32: k = quad*8+j within each 32-kv chunk), shared by qf
    f16x8 va[2][4];  // [kf=kv32-chunk][g=dh-frag]
#pragma unroll
    for (int kf = 0; kf < 2; kf++)
#pragma unroll
      for (int g = 0; g < 4; g++)
        va[kf][g] = *(const f16x8*)&Vls[(g * 16 + l16) * 64 + ((kf * 4 + quad) ^ sw) * 8];

    // p~ = 2^s, packed f16; accumulate row sums; P -> B-frags via permlane swaps
#pragma unroll
    for (int qf = 0; qf < 2; qf++) {
      union PK { hf16x2 r; f16x2 v; __half2 h; unsigned int u; };
      PK e01[4], e23[4];
      __half2 it2 = __half2{__half(0.f), __half(0.f)};
#pragma unroll
      for (int f = 0; f < 4; f++) {
        PK a01, a23;
        a01.r = __builtin_amdgcn_cvt_pkrtz(st[qf][f][0], st[qf][f][1]);
        a23.r = __builtin_amdgcn_cvt_pkrtz(st[qf][f][2], st[qf][f][3]);
        e01[f].h = h2exp2(a01.h);
        e23[f].h = h2exp2(a23.h);
        it2 = __hadd2(it2, __hadd2(e01[f].h, e23[f].h));
      }
      psum[qf] += __low2float(it2) + __high2float(it2);
      // in-register C->B redistribution (rows 8*qd+{0..7} per chunk kf)
#pragma unroll
      for (int kf = 0; kf < 2; kf++) {
        u32x2 sa = __builtin_amdgcn_permlane32_swap(e01[2 * kf].u, e01[2 * kf + 1].u, false, false);
        u32x2 sb = __builtin_amdgcn_permlane32_swap(e23[2 * kf].u, e23[2 * kf + 1].u, false, false);
        u32x2 ta = __builtin_amdgcn_permlane16_swap(sa[0], sa[1], false, false);
        u32x2 tb = __builtin_amdgcn_permlane16_swap(sb[0], sb[1], false, false);
        union { unsigned int u[4]; f16x8 v; } pb;
        pb.u[0] = ta[0];  // rows 8qd+{0,1}
        pb.u[1] = tb[0];  // rows 8qd+{2,3}
        pb.u[2] = ta[1];  // rows 8qd+{4,5}
        pb.u[3] = tb[1];  // rows 8qd+{6,7}
#pragma unroll
        for (int g = 0; g < 4; g++)
          Oacc[qf][g] = __builtin_amdgcn_mfma_f32_16x16x32_f16(va[kf][g], pb.v, Oacc[qf][g], 0, 0, 0);
      }
    }

    QDRAIN();   // next tile's 4 gld16 per thread: issued at iter start, L2-warm
    QBAR();
  }

  // psum: lanes with same l16 across the 4 quads hold disjoint kv subsets
  float inv[2];
#pragma unroll
  for (int qf = 0; qf < 2; qf++) {
    float v = psum[qf];
    v += __shfl_xor(v, 16);
    v += __shfl_xor(v, 32);
    inv[qf] = 1.f / v;
  }

  // epilogue: O^T (col=q, row=dh) -> LDS transpose -> coalesced row-major store
  // (loop ended with a barrier; whole smem block reusable; 128 rows x 72 pitch)
  u16* Ols = (u16*)smem;
#pragma unroll
  for (int qf = 0; qf < 2; qf++)
#pragma unroll
    for (int g = 0; g < 4; g++) {
      u16x4 o;
#pragma unroll
      for (int r = 0; r < 4; r++) o[r] = f2bf(Oacc[qf][g][r] * inv[qf]);
      *(u16x4*)&Ols[(wave * 32 + qf * 16 + l16) * 72 + g * 16 + quad * 4] = o;
    }
  __syncthreads();
  // 128 rows x 64 dh; 2 threads per row, 32 u16 each (4x u16x8)
  const int orow = t >> 1, ocol = (t & 1) * 32;
  u16* gO = Ob + (size_t)(b * 2048 + q0 + orow) * 1024 + h * 64 + ocol;
#pragma unroll
  for (int j = 0; j < 4; j++)
    *(u16x8*)(gO + j * 8) = *(const u16x8*)&Ols[orow * 72 + ocol + j * 8];
}

// ---------------- LayerNorm (bf16 input, fp32 output) ----------------

__global__ __launch_bounds__(256) void k_ln(const u16* __restrict__ y,
                                            const float* __restrict__ g,
                                            const float* __restrict__ bt,
                                            float* __restrict__ out) {
  const int row = blockIdx.x;
  const int t = threadIdx.x;
  u16x4 rv = *(const u16x4*)(y + row * 1024 + t * 4);
  float vx = bf2f(rv[0]), vy = bf2f(rv[1]), vz = bf2f(rv[2]), vw = bf2f(rv[3]);
  float s1 = vx + vy + vz + vw;
  float s2 = vx * vx + vy * vy + vz * vz + vw * vw;
#pragma unroll
  for (int off = 32; off; off >>= 1) {
    s1 += __shfl_down(s1, off);
    s2 += __shfl_down(s2, off);
  }
  __shared__ float red[10];
  const int wave = t >> 6, lane = t & 63;
  if (lane == 0) { red[wave] = s1; red[4 + wave] = s2; }
  __syncthreads();
  if (t == 0) {
    float a = red[0] + red[1] + red[2] + red[3];
    float bsum = red[4] + red[5] + red[6] + red[7];
    float mean = a * (1.f / 1024.f);
    float var = bsum * (1.f / 1024.f) - mean * mean;
    red[8] = mean;
    red[9] = rsqrtf(var + 1e-6f);
  }
  __syncthreads();
  float mean = red[8], iv = red[9];
  float4 gv = *(const float4*)(g + t * 4);
  float4 bv = *(const float4*)(bt + t * 4);
  float4 o;
  o.x = (vx - mean) * iv * gv.x + bv.x;
  o.y = (vy - mean) * iv * gv.y + bv.y;
  o.z = (vz - mean) * iv * gv.z + bv.z;
  o.w = (vw - mean) * iv * gv.w + bv.w;
  *(float4*)(out + row * 1024 + t * 4) = o;
}

// ---------------- launch ----------------

extern "C" void kernel_launch(void* const* d_in, const int* in_sizes, int n_in,
                              void* d_out, int out_size, void* d_ws, size_t ws_size,
                              hipStream_t stream) {
  const float* x  = (const float*)d_in[0];
  const float* wq = (const float*)d_in[1];
  const float* wk = (const float*)d_in[2];
  const float* wv = (const float*)d_in[3];
  const float* wp = (const float*)d_in[4];
  const float* bp = (const float*)d_in[5];
  const float* g  = (const float*)d_in[6];
  const float* bt = (const float*)d_in[7];
  float* out = (float*)d_out;
  char* ws = (char*)d_ws;

  u16* xbf = (u16*)(ws);
  u16* wqT = (u16*)(ws + (16 << 20));        // [3072][1024] fused: wq|wk|wv
  u16* wkT = wqT + (size_t)1024 * 1024;
  u16* wvT = wqT + (size_t)2048 * 1024;
  u16* wpT = (u16*)(ws + (22 << 20));
  u16* Qb  = (u16*)(ws + (24 << 20));
  u16* Kb  = (u16*)(ws + (40 << 20));
  u16* VbT = (u16*)(ws + (56 << 20));
  u16* Ob  = (u16*)(ws);                   // aliases xbf (dead after QKV GEMM)
  u16* ypre = (u16*)(ws + (24 << 20));     // bf16, aliases Qb (dead after attention)

  k_conv<<<5120, 256, 0, stream>>>(x, xbf, wq, wk, wv, wp, wqT, wkT, wvT, wpT);
  k_gemm_qkv<<<dim3(32, 24), 512, 0, stream>>>(xbf, wqT, Qb, Kb, VbT);
  k_attn<<<dim3(64, 16), 256, 0, stream>>>(Qb, Kb, VbT, Ob);
  k_gemm_proj<<<dim3(32, 8), 512, 0, stream>>>(Ob, wpT, x, bp, ypre);
  k_ln<<<8192, 256, 0, stream>>>(ypre, g, bt, out);
}

// Round 9
// 278.975 us; speedup vs baseline: 1.0021x; 1.0021x over previous
//
#include <hip/hip_runtime.h>
#include <hip/hip_fp16.h>

// Fused MHA block: y = LN(x + b_proj + softmax(QK^T/8) V W_proj), MFMA compute.
// B=4, S=2048, D=1024, H=16, Dh=64.  M = B*S = 8192.
//
// Workspace layout (needs ~72 MB; aliased):
//   [0,16M)   x_bf16 [8192][1024]     -- later reused as O bf16 [8192][1024]
//   [16,22M)  wqkvT bf16 [3072n][1024k]  (wq/wk/wv transposed, contiguous)
//   [22,24M)  wprojT bf16 [1024n][1024k]
//   [24,40M)  Q bf16 [8192][1024]  (PRE-SCALED by 0.125*log2e; n = h*64+dh)
//   [40,56M)  K bf16
//   [56,72M)  V^T f16 [b][h][dh][s]   (written transposed+f16 by QKV GEMM epilogue)
//   [24,40M)  y_pre bf16 [8192][1024]  (aliases Q after attention)

typedef unsigned short u16;
typedef __attribute__((ext_vector_type(8))) u16 u16x8;
typedef __attribute__((ext_vector_type(4))) u16 u16x4;
typedef __attribute__((ext_vector_type(2))) unsigned int u32x2;
typedef __attribute__((ext_vector_type(8))) __bf16 bf16x8;
typedef __attribute__((ext_vector_type(8))) _Float16 f16x8;
typedef __attribute__((ext_vector_type(4))) _Float16 f16x4;
typedef __attribute__((ext_vector_type(2))) _Float16 f16x2;
typedef __attribute__((ext_vector_type(2))) __fp16 hf16x2;   // cvt_pkrtz return type
typedef __attribute__((ext_vector_type(4))) float f32x4;

#define SM_C1 0.1803368801111204f   /* 0.125 * log2(e) */

static __device__ __forceinline__ u16 f2bf(float f) {
  union { float f; unsigned int u; } v; v.f = f;
  unsigned int u = v.u;
  return (u16)((u + 0x7fffu + ((u >> 16) & 1u)) >> 16);  // RNE
}
static __device__ __forceinline__ float bf2f(u16 b) {
  union { unsigned int u; float f; } v; v.u = ((unsigned int)b) << 16;
  return v.f;
}
static __device__ __forceinline__ u16 f2h(float f) {
  union { _Float16 h; u16 u; } v; v.h = (_Float16)f;  // v_cvt_f16_f32, RNE
  return v.u;
}

// async global->LDS, 16B per lane; LDS dest = wave-uniform base + lane*16
static __device__ __forceinline__ void gld16(const u16* g, u16* l) {
  __builtin_amdgcn_global_load_lds((const __attribute__((address_space(1))) void*)g,
                                   (__attribute__((address_space(3))) void*)l, 16, 0, 0);
}

// raw barrier with compiler memory fences (no sched_barrier pinning)
#define QBAR() do { asm volatile("" ::: "memory"); __builtin_amdgcn_s_barrier(); \
                    asm volatile("" ::: "memory"); } while (0)
#define QDRAIN() asm volatile("s_waitcnt vmcnt(0)" ::: "memory")
#define QWAIT6() asm volatile("s_waitcnt vmcnt(6)" ::: "memory")

// ---------------- fused conversion kernel ----------------
// blocks [0,4096): x fp32 -> bf16 (vectorized)
// blocks [4096,5120): 4x 1024x1024 fp32 -> bf16 [n][k] transpose (LDS tiled)

__global__ __launch_bounds__(256) void k_conv(const float* __restrict__ x,
                                              u16* __restrict__ xbf,
                                              const float* __restrict__ w0,
                                              const float* __restrict__ w1,
                                              const float* __restrict__ w2,
                                              const float* __restrict__ w3,
                                              u16* __restrict__ o0, u16* __restrict__ o1,
                                              u16* __restrict__ o2, u16* __restrict__ o3) {
  __shared__ float tile[64][65];
  const int t = threadIdx.x;
  if (blockIdx.x < 4096) {
    int i = (blockIdx.x * 256 + t) * 8;
    float4 a = *(const float4*)(x + i);
    float4 b = *(const float4*)(x + i + 4);
    u16x8 o;
    o[0] = f2bf(a.x); o[1] = f2bf(a.y); o[2] = f2bf(a.z); o[3] = f2bf(a.w);
    o[4] = f2bf(b.x); o[5] = f2bf(b.y); o[6] = f2bf(b.z); o[7] = f2bf(b.w);
    *(u16x8*)(xbf + i) = o;
    return;
  }
  const int id = blockIdx.x - 4096;          // 0..1023
  const int z = id >> 8, rem = id & 255;
  const int k0 = (rem & 15) * 64, n0 = (rem >> 4) * 64;
  const float* w = z == 0 ? w0 : z == 1 ? w1 : z == 2 ? w2 : w3;
  u16* o = z == 0 ? o0 : z == 1 ? o1 : z == 2 ? o2 : o3;
#pragma unroll
  for (int i = 0; i < 16; i++) {
    int idx = t + 256 * i;
    int k = idx >> 6, n = idx & 63;
    tile[k][n] = w[(k0 + k) * 1024 + n0 + n];
  }
  __syncthreads();
#pragma unroll
  for (int i = 0; i < 16; i++) {
    int idx = t + 256 * i;
    int n = idx >> 6, k = idx & 63;
    o[(n0 + n) * 1024 + k0 + k] = f2bf(tile[k][n]);
  }
}

// ---------------- QKV GEMM: 256x128 tile, counted-vmcnt double-buffer ----------------
// grid (32,24) = 768 blocks = exactly 3 waves of 256 CUs (zero tail), 96 KB LDS,
// 512 thr = 8 waves as 4Mx2N; per-wave tile 64x64 (acc[4][4], m97 frag pattern,
// same XOR-swizzled reads, bit-identical accumulation order).
// Per K-tile: { STAGE(t+1) issue; s_waitcnt vmcnt(6); barrier; ds_read frags;
// 32 MFMA; barrier }.  NO vmcnt(0) in the loop.

__global__ __launch_bounds__(512, 2) void k_gemm_qkv(const u16* __restrict__ xbf,
                                                     const u16* __restrict__ wT,
                                                     u16* __restrict__ Qb, u16* __restrict__ Kb,
                                                     u16* __restrict__ VbT) {
  __shared__ alignas(16) u16 As[2][256 * 64];
  __shared__ alignas(16) u16 Bs[2][128 * 64];
  const int t = threadIdx.x;
  const int wv = t >> 6, lane = t & 63, quad = lane >> 4, l16 = lane & 15;
  const int wm = wv >> 1, wn = wv & 1;       // 4M x 2N wave grid
  const int m0 = blockIdx.x * 256;
  const int nt = blockIdx.y;                 // 0..23 (8 per matrix)
  const int srow = t >> 3;                   // staging row 0..63 (+64 per issue)
  const int kg = (t & 7) ^ (srow & 7);       // swizzled k-granule
  const u16* aG = xbf + (size_t)(m0 + srow) * 1024 + kg * 8;
  const u16* bG = wT + (size_t)(nt * 128 + srow) * 1024 + kg * 8;
  const int sw = l16 & 7;
  const int ldsDst = wv * 512;               // wave-uniform dest (u16 units) per issue

  f32x4 acc[4][4] = {};

  auto STAGE = [&](int tl) {
    const int p_ = tl & 1;
    const int k0_ = tl * 64;
#pragma unroll
    for (int i = 0; i < 4; i++)   // A: 256 rows, 64 per issue
      gld16(aG + (size_t)i * 64 * 1024 + k0_, &As[p_][i * 4096 + ldsDst]);
#pragma unroll
    for (int i = 0; i < 2; i++)   // B: 128 rows
      gld16(bG + (size_t)i * 64 * 1024 + k0_, &Bs[p_][i * 4096 + ldsDst]);
  };

  STAGE(0);

#pragma unroll 2
  for (int tile = 0; tile < 16; ++tile) {
    const int p = tile & 1;
    if (tile < 15) { STAGE(tile + 1); QWAIT6(); }
    else           { QDRAIN(); }
    QBAR();   // all waves' tile-t loads landed -> buf[p] fully populated

    bf16x8 a[4][2], b[4][2];
#pragma unroll
    for (int f = 0; f < 4; f++)
#pragma unroll
      for (int kk = 0; kk < 2; kk++)
        a[f][kk] = *(const bf16x8*)&As[p][(wm * 64 + f * 16 + l16) * 64 +
                                          ((kk * 4 + quad) ^ sw) * 8];
#pragma unroll
    for (int g = 0; g < 4; g++)
#pragma unroll
      for (int kk = 0; kk < 2; kk++)
        b[g][kk] = *(const bf16x8*)&Bs[p][(wn * 64 + g * 16 + l16) * 64 +
                                          ((kk * 4 + quad) ^ sw) * 8];
#pragma unroll
    for (int f = 0; f < 4; f++)
#pragma unroll
      for (int g = 0; g < 4; g++)
#pragma unroll
        for (int kk = 0; kk < 2; kk++)
          acc[f][g] = __builtin_amdgcn_mfma_f32_16x16x32_bf16(a[f][kk], b[g][kk], acc[f][g], 0, 0, 0);

    QBAR();   // reads of buf[p] done block-wide -> safe to recycle next iter
  }

  const int sel = nt >> 3;
  const int n0 = (nt & 7) * 128 + wn * 64;
  const int mBase = m0 + wm * 64 + quad * 4;
  if (sel < 2) {
    u16* Ob = sel == 0 ? Qb : Kb;
    const float scl = sel == 0 ? SM_C1 : 1.0f;
#pragma unroll
    for (int f = 0; f < 4; f++)
#pragma unroll
      for (int g = 0; g < 4; g++)
#pragma unroll
        for (int r = 0; r < 4; r++) {
          int m = mBase + f * 16 + r;
          int n = n0 + g * 16 + l16;
          Ob[(size_t)m * 1024 + n] = f2bf(acc[f][g][r] * scl);
        }
  } else {
    // V^T f16: [b][h][dh][s]; 4 r-values are 4 consecutive s -> one 8B store
#pragma unroll
    for (int f = 0; f < 4; f++) {
      int m = mBase + f * 16;
      int bb = m >> 11, s = m & 2047;
#pragma unroll
      for (int g = 0; g < 4; g++) {
        int n = n0 + g * 16 + l16;
        int hh = n >> 6, dh = n & 63;
        u16x4 o;
#pragma unroll
        for (int r = 0; r < 4; r++) o[r] = f2h(acc[f][g][r]);
        *(u16x4*)&VbT[(size_t)(((bb << 4) + hh) * 64 + dh) * 2048 + s] = o;
      }
    }
  }
}

// ---------------- proj GEMM + bias + residual (m97 128^2, REVERTED) ----------------
// r8's counted-vmcnt 256x128 port (grid (32,8) = 1 block/CU) regressed the
// non-attn residue ~13us: proj is a small GEMM (17 GFLOP) where TLP matters
// more than pipeline depth, and 1 block/CU strangles the epilogue's 32 MB
// fp32 x-read overlap.  m97 128^2: grid (64,8) = 512 blocks ~3/CU (proven).

__global__ __launch_bounds__(256) void k_gemm_proj(const u16* __restrict__ Abf,
                                                   const u16* __restrict__ wT,
                                                   const float* __restrict__ x,
                                                   const float* __restrict__ bias,
                                                   u16* __restrict__ ypre) {
  __shared__ alignas(16) u16 Als[128 * 64];
  __shared__ alignas(16) u16 Bls[128 * 64];
  const int t = threadIdx.x;
  const int wv = t >> 6, lane = t & 63, quad = lane >> 4, l16 = lane & 15;
  const int wm = wv >> 1, wn = wv & 1;
  const int m0 = blockIdx.x * 128;
  const int n0t = blockIdx.y * 128;
  const int row = t >> 3;
  const int kg = (t & 7) ^ (row & 7);
  const u16* aG = Abf + (size_t)(m0 + row) * 1024 + kg * 8;
  const u16* bG = wT + (size_t)(n0t + row) * 1024 + kg * 8;
  const int sw = l16 & 7;
  const int aA0 = (wm * 64 + l16) * 64 + ((quad) ^ sw) * 8;
  const int aA1 = (wm * 64 + l16) * 64 + ((4 + quad) ^ sw) * 8;
  const int bA0 = (wn * 64 + l16) * 64 + ((quad) ^ sw) * 8;
  const int bA1 = (wn * 64 + l16) * 64 + ((4 + quad) ^ sw) * 8;

  f32x4 acc[4][4] = {};
  for (int k0 = 0; k0 < 1024; k0 += 64) {
    __syncthreads();
#pragma unroll
    for (int i = 0; i < 4; i++) {
      gld16(aG + i * 32 * 1024 + k0, &Als[(i * 256 + wv * 64) * 8]);
      gld16(bG + i * 32 * 1024 + k0, &Bls[(i * 256 + wv * 64) * 8]);
    }
    __syncthreads();
#pragma unroll
    for (int c = 0; c < 2; c++) {
      bf16x8 a[4], b[4];
#pragma unroll
      for (int f = 0; f < 4; f++) a[f] = *(const bf16x8*)&Als[(c ? aA1 : aA0) + f * 1024];
#pragma unroll
      for (int g = 0; g < 4; g++) b[g] = *(const bf16x8*)&Bls[(c ? bA1 : bA0) + g * 1024];
#pragma unroll
      for (int f = 0; f < 4; f++)
#pragma unroll
        for (int g = 0; g < 4; g++)
          acc[f][g] = __builtin_amdgcn_mfma_f32_16x16x32_bf16(a[f], b[g], acc[f][g], 0, 0, 0);
    }
  }

  const int n0 = n0t + wn * 64;
  const int mBase = m0 + wm * 64 + quad * 4;
#pragma unroll
  for (int g = 0; g < 4; g++) {
    int n = n0 + g * 16 + l16;
    float bn = bias[n];
#pragma unroll
    for (int f = 0; f < 4; f++)
#pragma unroll
      for (int r = 0; r < 4; r++) {
        int m = mBase + f * 16 + r;
        ypre[(size_t)m * 1024 + n] = f2bf(acc[f][g][r] + bn + x[(size_t)m * 1024 + n]);
      }
  }
}

// ---------------- flash attention (transposed-score form, 128-q blocks) ----------------
// q-block 128 (grid (64,16) = 1024 blocks = 4 blocks/CU, launch_bounds(256,4)).
// r8 measured: Occupancy 29.7, VALUBusy 59 + MfmaUtil 37 = 96% pipe-sum ->
// issue-bound on the exp/cvt/permlane stream overlapped with MFMA; this is the
// structural ceiling of this decomposition (~81 us).  VGPR 64.
// S^T = K Q_scaled^T (16x16x32 bf16); p~ = 2^s packed-f16 exp; PV full-rate
// 16x16x32 f16 with in-register C->B redistribution via permlane swaps.
// K/V staging via global_load_lds into linear [64][64] buffers, XOR-granule
// swizzle on the GLOBAL source address; frag reads swizzle by ^(l16&7)
// (bank conflicts 197K).  No setprio (m190 null regime).

__global__ __launch_bounds__(256, 4) void k_attn(const u16* __restrict__ Qb,
                                                 const u16* __restrict__ Kb,
                                                 const u16* __restrict__ VbT,
                                                 u16* __restrict__ Ob) {
  // [0..1]: K ping/pong [64][64] bf16; [2..3]: V ping/pong [64][64] f16.
  // Regions padded to 64*72 so the O-epilogue transpose (128 rows x 72) fits.
  __shared__ alignas(16) u16 smem[4][64 * 72];
  const int b = blockIdx.x >> 4, h = blockIdx.x & 15;
  const int q0 = blockIdx.y * 128;
  const int t = threadIdx.x;
  const int wave = t >> 6, lane = t & 63, quad = lane >> 4, l16 = lane & 15;
  const int sw = l16 & 7;

  // Q fragments (pre-scaled); wave owns 32 q rows (2 q-frags)
  bf16x8 aq[2][2];
#pragma unroll
  for (int qf = 0; qf < 2; qf++)
#pragma unroll
    for (int c = 0; c < 2; c++)
      aq[qf][c] = *(const bf16x8*)&Qb[(size_t)(b * 2048 + q0 + wave * 32 + qf * 16 + l16) * 1024 +
                                      h * 64 + c * 32 + quad * 8];

  f32x4 Oacc[2][4] = {};   // [qf][dh-frag g]; C-layout col=q, row=dh_local
  float psum[2] = {};      // per-lane partial row sum for q=l16 (per qf)

  const u16* kBase = Kb + (size_t)(b * 2048) * 1024 + h * 64;
  const u16* vBase = VbT + (size_t)((b * 16 + h) * 64) * 2048;

  // staging: slot s = i*256 + t covers (row r = s>>3, granule gslot = s&7);
  // source granule = gslot ^ (r&7); LDS dest linear = s*16B (base wave-uniform).
  const int sRow0 = t >> 3, sG0 = (t & 7) ^ (sRow0 & 7);          // i=0
  const int sRow1 = (256 + t) >> 3, sG1 = (t & 7) ^ (sRow1 & 7);  // i=1

  auto STAGE = [&](int kt, int p) {
    const int kv = kt * 64;
    u16* Kls = smem[p];
    u16* Vls = smem[2 + p];
    gld16(kBase + (size_t)(kv + sRow0) * 1024 + sG0 * 8, &Kls[(wave * 64) * 8]);
    gld16(kBase + (size_t)(kv + sRow1) * 1024 + sG1 * 8, &Kls[(256 + wave * 64) * 8]);
    gld16(vBase + (size_t)sRow0 * 2048 + kv + sG0 * 8, &Vls[(wave * 64) * 8]);
    gld16(vBase + (size_t)sRow1 * 2048 + kv + sG1 * 8, &Vls[(256 + wave * 64) * 8]);
  };

  STAGE(0, 0);
  QDRAIN();
  QBAR();

  for (int kt = 0; kt < 32; kt++) {
    const int p = kt & 1;
    u16* Kls = smem[p];
    u16* Vls = smem[2 + p];
    if (kt < 31) STAGE(kt + 1, p ^ 1);   // flies across this iter's compute

    // S^T = K Q^T : A = K-frag (m=kv), B = Q-frag (n=q)
    f32x4 st[2][4];   // [qf][kv-frag f]
#pragma unroll
    for (int qf = 0; qf < 2; qf++)
#pragma unroll
      for (int f = 0; f < 4; f++) st[qf][f] = f32x4{0.f, 0.f, 0.f, 0.f};
#pragma unroll
    for (int c = 0; c < 2; c++) {
      bf16x8 bk[4];
#pragma unroll
      for (int f = 0; f < 4; f++)
        bk[f] = *(const bf16x8*)&Kls[(f * 16 + l16) * 64 + ((c * 4 + quad) ^ sw) * 8];
#pragma unroll
      for (int qf = 0; qf < 2; qf++)
#pragma unroll
        for (int f = 0; f < 4; f++)
          st[qf][f] = __builtin_amdgcn_mfma_f32_16x16x32_bf16(bk[f], aq[qf][c], st[qf][f], 0, 0, 0);
    }

    // V A-operand frags (K=32: k = quad*8+j within each 32-kv chunk), shared by qf
    f16x8 va[2][4];  // [kf=kv32-chunk][g=dh-frag]
#pragma unroll
    for (int kf = 0; kf < 2; kf++)
#pragma unroll
      for (int g = 0; g < 4; g++)
        va[kf][g] = *(const f16x8*)&Vls[(g * 16 + l16) * 64 + ((kf * 4 + quad) ^ sw) * 8];

    // p~ = 2^s, packed f16; accumulate row sums; P -> B-frags via permlane swaps
#pragma unroll
    for (int qf = 0; qf < 2; qf++) {
      union PK { hf16x2 r; f16x2 v; __half2 h; unsigned int u; };
      PK e01[4], e23[4];
      __half2 it2 = __half2{__half(0.f), __half(0.f)};
#pragma unroll
      for (int f = 0; f < 4; f++) {
        PK a01, a23;
        a01.r = __builtin_amdgcn_cvt_pkrtz(st[qf][f][0], st[qf][f][1]);
        a23.r = __builtin_amdgcn_cvt_pkrtz(st[qf][f][2], st[qf][f][3]);
        e01[f].h = h2exp2(a01.h);
        e23[f].h = h2exp2(a23.h);
        it2 = __hadd2(it2, __hadd2(e01[f].h, e23[f].h));
      }
      psum[qf] += __low2float(it2) + __high2float(it2);
      // in-register C->B redistribution (rows 8*qd+{0..7} per chunk kf)
#pragma unroll
      for (int kf = 0; kf < 2; kf++) {
        u32x2 sa = __builtin_amdgcn_permlane32_swap(e01[2 * kf].u, e01[2 * kf + 1].u, false, false);
        u32x2 sb = __builtin_amdgcn_permlane32_swap(e23[2 * kf].u, e23[2 * kf + 1].u, false, false);
        u32x2 ta = __builtin_amdgcn_permlane16_swap(sa[0], sa[1], false, false);
        u32x2 tb = __builtin_amdgcn_permlane16_swap(sb[0], sb[1], false, false);
        union { unsigned int u[4]; f16x8 v; } pb;
        pb.u[0] = ta[0];  // rows 8qd+{0,1}
        pb.u[1] = tb[0];  // rows 8qd+{2,3}
        pb.u[2] = ta[1];  // rows 8qd+{4,5}
        pb.u[3] = tb[1];  // rows 8qd+{6,7}
#pragma unroll
        for (int g = 0; g < 4; g++)
          Oacc[qf][g] = __builtin_amdgcn_mfma_f32_16x16x32_f16(va[kf][g], pb.v, Oacc[qf][g], 0, 0, 0);
      }
    }

    QDRAIN();   // next tile's 4 gld16 per thread: issued at iter start, L2-warm
    QBAR();
  }

  // psum: lanes with same l16 across the 4 quads hold disjoint kv subsets
  float inv[2];
#pragma unroll
  for (int qf = 0; qf < 2; qf++) {
    float v = psum[qf];
    v += __shfl_xor(v, 16);
    v += __shfl_xor(v, 32);
    inv[qf] = 1.f / v;
  }

  // epilogue: O^T (col=q, row=dh) -> LDS transpose -> coalesced row-major store
  // (loop ended with a barrier; whole smem block reusable; 128 rows x 72 pitch)
  u16* Ols = (u16*)smem;
#pragma unroll
  for (int qf = 0; qf < 2; qf++)
#pragma unroll
    for (int g = 0; g < 4; g++) {
      u16x4 o;
#pragma unroll
      for (int r = 0; r < 4; r++) o[r] = f2bf(Oacc[qf][g][r] * inv[qf]);
      *(u16x4*)&Ols[(wave * 32 + qf * 16 + l16) * 72 + g * 16 + quad * 4] = o;
    }
  __syncthreads();
  // 128 rows x 64 dh; 2 threads per row, 32 u16 each (4x u16x8)
  const int orow = t >> 1, ocol = (t & 1) * 32;
  u16* gO = Ob + (size_t)(b * 2048 + q0 + orow) * 1024 + h * 64 + ocol;
#pragma unroll
  for (int j = 0; j < 4; j++)
    *(u16x8*)(gO + j * 8) = *(const u16x8*)&Ols[orow * 72 + ocol + j * 8];
}

// ---------------- LayerNorm (bf16 input, fp32 output) ----------------

__global__ __launch_bounds__(256) void k_ln(const u16* __restrict__ y,
                                            const float* __restrict__ g,
                                            const float* __restrict__ bt,
                                            float* __restrict__ out) {
  const int row = blockIdx.x;
  const int t = threadIdx.x;
  u16x4 rv = *(const u16x4*)(y + row * 1024 + t * 4);
  float vx = bf2f(rv[0]), vy = bf2f(rv[1]), vz = bf2f(rv[2]), vw = bf2f(rv[3]);
  float s1 = vx + vy + vz + vw;
  float s2 = vx * vx + vy * vy + vz * vz + vw * vw;
#pragma unroll
  for (int off = 32; off; off >>= 1) {
    s1 += __shfl_down(s1, off);
    s2 += __shfl_down(s2, off);
  }
  __shared__ float red[10];
  const int wave = t >> 6, lane = t & 63;
  if (lane == 0) { red[wave] = s1; red[4 + wave] = s2; }
  __syncthreads();
  if (t == 0) {
    float a = red[0] + red[1] + red[2] + red[3];
    float bsum = red[4] + red[5] + red[6] + red[7];
    float mean = a * (1.f / 1024.f);
    float var = bsum * (1.f / 1024.f) - mean * mean;
    red[8] = mean;
    red[9] = rsqrtf(var + 1e-6f);
  }
  __syncthreads();
  float mean = red[8], iv = red[9];
  float4 gv = *(const float4*)(g + t * 4);
  float4 bv = *(const float4*)(bt + t * 4);
  float4 o;
  o.x = (vx - mean) * iv * gv.x + bv.x;
  o.y = (vy - mean) * iv * gv.y + bv.y;
  o.z = (vz - mean) * iv * gv.z + bv.z;
  o.w = (vw - mean) * iv * gv.w + bv.w;
  *(float4*)(out + row * 1024 + t * 4) = o;
}

// ---------------- launch ----------------

extern "C" void kernel_launch(void* const* d_in, const int* in_sizes, int n_in,
                              void* d_out, int out_size, void* d_ws, size_t ws_size,
                              hipStream_t stream) {
  const float* x  = (const float*)d_in[0];
  const float* wq = (const float*)d_in[1];
  const float* wk = (const float*)d_in[2];
  const float* wv = (const float*)d_in[3];
  const float* wp = (const float*)d_in[4];
  const float* bp = (const float*)d_in[5];
  const float* g  = (const float*)d_in[6];
  const float* bt = (const float*)d_in[7];
  float* out = (float*)d_out;
  char* ws = (char*)d_ws;

  u16* xbf = (u16*)(ws);
  u16* wqT = (u16*)(ws + (16 << 20));        // [3072][1024] fused: wq|wk|wv
  u16* wkT = wqT + (size_t)1024 * 1024;
  u16* wvT = wqT + (size_t)2048 * 1024;
  u16* wpT = (u16*)(ws + (22 << 20));
  u16* Qb  = (u16*)(ws + (24 << 20));
  u16* Kb  = (u16*)(ws + (40 << 20));
  u16* VbT = (u16*)(ws + (56 << 20));
  u16* Ob  = (u16*)(ws);                   // aliases xbf (dead after QKV GEMM)
  u16* ypre = (u16*)(ws + (24 << 20));     // bf16, aliases Qb (dead after attention)

  k_conv<<<5120, 256, 0, stream>>>(x, xbf, wq, wk, wv, wp, wqT, wkT, wvT, wpT);
  k_gemm_qkv<<<dim3(32, 24), 512, 0, stream>>>(xbf, wqT, Qb, Kb, VbT);
  k_attn<<<dim3(64, 16), 256, 0, stream>>>(Qb, Kb, VbT, Ob);
  k_gemm_proj<<<dim3(64, 8), 256, 0, stream>>>(Ob, wpT, x, bp, ypre);
  k_ln<<<8192, 256, 0, stream>>>(ypre, g, bt, out);
}

// Round 10
// 265.870 us; speedup vs baseline: 1.0515x; 1.0493x over previous
//
#include <hip/hip_runtime.h>
#include <hip/hip_fp16.h>

// Fused MHA block: y = LN(x + b_proj + softmax(QK^T/8) V W_proj), MFMA compute.
// B=4, S=2048, D=1024, H=16, Dh=64.  M = B*S = 8192.
//
// FINAL CONFIG (best-measured, r5 bench = 268.1 us): gld16-staged 256-q attn,
// m97-128^2 QKV (grid 64x24, ~6 blocks/CU), m97 proj, separate conv kernels.
// Session noise (±5-10 us) exceeds all remaining single-variable deltas
// (r6-r9 ledger); attn is issue-bound (~90% pipe-sum, occupancy-insensitive),
// QKV at the 2-barrier structure's plateau.
//
// Workspace layout (needs ~72 MB; aliased):
//   [0,16M)   x_bf16 [8192][1024]     -- later reused as O bf16 [8192][1024]
//   [16,22M)  wqkvT bf16 [3072n][1024k]  (wq/wk/wv transposed, contiguous)
//   [22,24M)  wprojT bf16 [1024n][1024k]
//   [24,40M)  Q bf16 [8192][1024]  (PRE-SCALED by 0.125*log2e; n = h*64+dh)
//   [40,56M)  K bf16
//   [56,72M)  V^T f16 [b][h][dh][s]   (written transposed+f16 by QKV GEMM epilogue)
//   [24,40M)  y_pre bf16 [8192][1024]  (aliases Q after attention)

typedef unsigned short u16;
typedef __attribute__((ext_vector_type(8))) u16 u16x8;
typedef __attribute__((ext_vector_type(4))) u16 u16x4;
typedef __attribute__((ext_vector_type(2))) unsigned int u32x2;
typedef __attribute__((ext_vector_type(8))) __bf16 bf16x8;
typedef __attribute__((ext_vector_type(8))) _Float16 f16x8;
typedef __attribute__((ext_vector_type(4))) _Float16 f16x4;
typedef __attribute__((ext_vector_type(2))) _Float16 f16x2;
typedef __attribute__((ext_vector_type(2))) __fp16 hf16x2;   // cvt_pkrtz return type
typedef __attribute__((ext_vector_type(4))) float f32x4;

#define SM_C1 0.1803368801111204f   /* 0.125 * log2(e) */

static __device__ __forceinline__ u16 f2bf(float f) {
  union { float f; unsigned int u; } v; v.f = f;
  unsigned int u = v.u;
  return (u16)((u + 0x7fffu + ((u >> 16) & 1u)) >> 16);  // RNE
}
static __device__ __forceinline__ float bf2f(u16 b) {
  union { unsigned int u; float f; } v; v.u = ((unsigned int)b) << 16;
  return v.f;
}
static __device__ __forceinline__ u16 f2h(float f) {
  union { _Float16 h; u16 u; } v; v.h = (_Float16)f;  // v_cvt_f16_f32, RNE
  return v.u;
}

// async global->LDS, 16B per lane; LDS dest = wave-uniform base + lane*16
static __device__ __forceinline__ void gld16(const u16* g, u16* l) {
  __builtin_amdgcn_global_load_lds((const __attribute__((address_space(1))) void*)g,
                                   (__attribute__((address_space(3))) void*)l, 16, 0, 0);
}

// raw barrier with compiler memory fences (no sched_barrier pinning)
#define QBAR() do { asm volatile("" ::: "memory"); __builtin_amdgcn_s_barrier(); \
                    asm volatile("" ::: "memory"); } while (0)
#define QDRAIN() asm volatile("s_waitcnt vmcnt(0)" ::: "memory")

// ---------------- conversion kernels ----------------

__global__ __launch_bounds__(256) void k_convx(const float* __restrict__ x,
                                               u16* __restrict__ xbf) {
  int i = (blockIdx.x * 256 + threadIdx.x) * 8;
  float4 a = *(const float4*)(x + i);
  float4 b = *(const float4*)(x + i + 4);
  u16x8 o;
  o[0] = f2bf(a.x); o[1] = f2bf(a.y); o[2] = f2bf(a.z); o[3] = f2bf(a.w);
  o[4] = f2bf(b.x); o[5] = f2bf(b.y); o[6] = f2bf(b.z); o[7] = f2bf(b.w);
  *(u16x8*)(xbf + i) = o;
}

// transpose 1024x1024 fp32 -> bf16 [n][k], LDS tiled, both sides coalesced
__global__ __launch_bounds__(256) void k_convwT(const float* __restrict__ w0,
                                                const float* __restrict__ w1,
                                                const float* __restrict__ w2,
                                                const float* __restrict__ w3,
                                                u16* __restrict__ o0, u16* __restrict__ o1,
                                                u16* __restrict__ o2, u16* __restrict__ o3) {
  __shared__ float tile[64][65];
  const float* w = blockIdx.z == 0 ? w0 : blockIdx.z == 1 ? w1 : blockIdx.z == 2 ? w2 : w3;
  u16* o = blockIdx.z == 0 ? o0 : blockIdx.z == 1 ? o1 : blockIdx.z == 2 ? o2 : o3;
  const int k0 = blockIdx.x * 64, n0 = blockIdx.y * 64;
  const int t = threadIdx.x;
#pragma unroll
  for (int i = 0; i < 16; i++) {
    int idx = t + 256 * i;
    int k = idx >> 6, n = idx & 63;
    tile[k][n] = w[(k0 + k) * 1024 + n0 + n];
  }
  __syncthreads();
#pragma unroll
  for (int i = 0; i < 16; i++) {
    int idx = t + 256 * i;
    int n = idx >> 6, k = idx & 63;
    o[(n0 + n) * 1024 + k0 + k] = f2bf(tile[k][n]);
  }
}

// ---------------- QKV GEMM (m97 structure, 128x128) ----------------
// grid (64,24) = 1536 blocks ~6/CU (TLP; 256^2 variants quantize badly on this
// problem's M=8192,N=3072 -- r3/r4/r6 experiments bracketed this plateau).
// Staging via global_load_lds dwordx4; XOR-swizzled granules (kg = pg ^ (row&7))
// so ds_read_b128 fragment reads are bank-conflict-free without padding.
// wT is the fused [3072][1024] (wq|wk|wv transposed). sel: 0 -> Q bf16*SM_C1;
// 1 -> K bf16 row-major; 2 -> V^T f16 [b][h][dh][s].

__global__ __launch_bounds__(256) void k_gemm_qkv(const u16* __restrict__ xbf,
                                                  const u16* __restrict__ wT,
                                                  u16* __restrict__ Qb, u16* __restrict__ Kb,
                                                  u16* __restrict__ VbT) {
  __shared__ alignas(16) u16 Als[128 * 64];
  __shared__ alignas(16) u16 Bls[128 * 64];
  const int t = threadIdx.x;
  const int wv = t >> 6, lane = t & 63, quad = lane >> 4, l16 = lane & 15;
  const int wm = wv >> 1, wn = wv & 1;
  const int m0 = blockIdx.x * 128;
  const int nt = blockIdx.y;                 // 0..23
  const int row = t >> 3;                    // staging row 0..31 (+32 per issue)
  const int kg = (t & 7) ^ (row & 7);        // swizzled k-granule
  const u16* aG = xbf + (size_t)(m0 + row) * 1024 + kg * 8;
  const u16* bG = wT + (size_t)(nt * 128 + row) * 1024 + kg * 8;
  const int sw = l16 & 7;
  const int aA0 = (wm * 64 + l16) * 64 + ((quad) ^ sw) * 8;
  const int aA1 = (wm * 64 + l16) * 64 + ((4 + quad) ^ sw) * 8;
  const int bA0 = (wn * 64 + l16) * 64 + ((quad) ^ sw) * 8;
  const int bA1 = (wn * 64 + l16) * 64 + ((4 + quad) ^ sw) * 8;

  f32x4 acc[4][4] = {};
  for (int k0 = 0; k0 < 1024; k0 += 64) {
    __syncthreads();
#pragma unroll
    for (int i = 0; i < 4; i++) {
      gld16(aG + i * 32 * 1024 + k0, &Als[(i * 256 + wv * 64) * 8]);
      gld16(bG + i * 32 * 1024 + k0, &Bls[(i * 256 + wv * 64) * 8]);
    }
    __syncthreads();
#pragma unroll
    for (int c = 0; c < 2; c++) {
      bf16x8 a[4], b[4];
#pragma unroll
      for (int f = 0; f < 4; f++) a[f] = *(const bf16x8*)&Als[(c ? aA1 : aA0) + f * 1024];
#pragma unroll
      for (int g = 0; g < 4; g++) b[g] = *(const bf16x8*)&Bls[(c ? bA1 : bA0) + g * 1024];
#pragma unroll
      for (int f = 0; f < 4; f++)
#pragma unroll
        for (int g = 0; g < 4; g++)
          acc[f][g] = __builtin_amdgcn_mfma_f32_16x16x32_bf16(a[f], b[g], acc[f][g], 0, 0, 0);
    }
  }

  const int sel = nt >> 3;
  const int n0 = (nt & 7) * 128 + wn * 64;
  const int mBase = m0 + wm * 64 + quad * 4;
  if (sel < 2) {
    u16* Ob = sel == 0 ? Qb : Kb;
    const float scl = sel == 0 ? SM_C1 : 1.0f;
#pragma unroll
    for (int f = 0; f < 4; f++)
#pragma unroll
      for (int g = 0; g < 4; g++)
#pragma unroll
        for (int r = 0; r < 4; r++) {
          int m = mBase + f * 16 + r;
          int n = n0 + g * 16 + l16;
          Ob[(size_t)m * 1024 + n] = f2bf(acc[f][g][r] * scl);
        }
  } else {
    // V^T f16: [b][h][dh][s]; 4 r-values are 4 consecutive s -> one 8B store
#pragma unroll
    for (int f = 0; f < 4; f++) {
      int m = mBase + f * 16;
      int bb = m >> 11, s = m & 2047;
#pragma unroll
      for (int g = 0; g < 4; g++) {
        int n = n0 + g * 16 + l16;
        int hh = n >> 6, dh = n & 63;
        u16x4 o;
#pragma unroll
        for (int r = 0; r < 4; r++) o[r] = f2h(acc[f][g][r]);
        *(u16x4*)&VbT[(size_t)(((bb << 4) + hh) * 64 + dh) * 2048 + s] = o;
      }
    }
  }
}

// ---------------- proj GEMM + bias + residual (m97 structure) ----------------
// epilogue writes y_pre as bf16 (halves ypre HBM traffic; LN reads bf16)

__global__ __launch_bounds__(256) void k_gemm_proj(const u16* __restrict__ Abf,
                                                   const u16* __restrict__ wT,
                                                   const float* __restrict__ x,
                                                   const float* __restrict__ bias,
                                                   u16* __restrict__ ypre) {
  __shared__ alignas(16) u16 Als[128 * 64];
  __shared__ alignas(16) u16 Bls[128 * 64];
  const int t = threadIdx.x;
  const int wv = t >> 6, lane = t & 63, quad = lane >> 4, l16 = lane & 15;
  const int wm = wv >> 1, wn = wv & 1;
  const int m0 = blockIdx.x * 128;
  const int n0t = blockIdx.y * 128;
  const int row = t >> 3;
  const int kg = (t & 7) ^ (row & 7);
  const u16* aG = Abf + (size_t)(m0 + row) * 1024 + kg * 8;
  const u16* bG = wT + (size_t)(n0t + row) * 1024 + kg * 8;
  const int sw = l16 & 7;
  const int aA0 = (wm * 64 + l16) * 64 + ((quad) ^ sw) * 8;
  const int aA1 = (wm * 64 + l16) * 64 + ((4 + quad) ^ sw) * 8;
  const int bA0 = (wn * 64 + l16) * 64 + ((quad) ^ sw) * 8;
  const int bA1 = (wn * 64 + l16) * 64 + ((4 + quad) ^ sw) * 8;

  f32x4 acc[4][4] = {};
  for (int k0 = 0; k0 < 1024; k0 += 64) {
    __syncthreads();
#pragma unroll
    for (int i = 0; i < 4; i++) {
      gld16(aG + i * 32 * 1024 + k0, &Als[(i * 256 + wv * 64) * 8]);
      gld16(bG + i * 32 * 1024 + k0, &Bls[(i * 256 + wv * 64) * 8]);
    }
    __syncthreads();
#pragma unroll
    for (int c = 0; c < 2; c++) {
      bf16x8 a[4], b[4];
#pragma unroll
      for (int f = 0; f < 4; f++) a[f] = *(const bf16x8*)&Als[(c ? aA1 : aA0) + f * 1024];
#pragma unroll
      for (int g = 0; g < 4; g++) b[g] = *(const bf16x8*)&Bls[(c ? bA1 : bA0) + g * 1024];
#pragma unroll
      for (int f = 0; f < 4; f++)
#pragma unroll
        for (int g = 0; g < 4; g++)
          acc[f][g] = __builtin_amdgcn_mfma_f32_16x16x32_bf16(a[f], b[g], acc[f][g], 0, 0, 0);
    }
  }

  const int n0 = n0t + wn * 64;
  const int mBase = m0 + wm * 64 + quad * 4;
#pragma unroll
  for (int g = 0; g < 4; g++) {
    int n = n0 + g * 16 + l16;
    float bn = bias[n];
#pragma unroll
    for (int f = 0; f < 4; f++)
#pragma unroll
      for (int r = 0; r < 4; r++) {
        int m = mBase + f * 16 + r;
        ypre[(size_t)m * 1024 + n] = f2bf(acc[f][g][r] + bn + x[(size_t)m * 1024 + n]);
      }
  }
}

// ---------------- flash attention (transposed-score form, 256-q blocks) ----------------
// grid (B*H, S/256): q-blocks of one head land on one XCD (K/V L2 reuse).
// S^T = K Q_scaled^T (16x16x32 bf16); p~ = 2^s packed-f16 exp; PV full-rate
// 16x16x32 f16 with in-register C->B redistribution via permlane swaps.
// K/V staging via global_load_lds into linear [64][64] buffers with XOR-granule
// swizzle applied on the per-lane GLOBAL source address; frag reads swizzle the
// granule by ^(l16&7) -> conflict-free (bank conflicts measured 131K).
// Issue-bound at ~90% pipe-sum (r8 occupancy-doubling A/B: no effect) -- this
// decomposition's ceiling.  No setprio (m190 null regime, r3 A/B -2.2us).

__global__ __launch_bounds__(256, 2) void k_attn(const u16* __restrict__ Qb,
                                                 const u16* __restrict__ Kb,
                                                 const u16* __restrict__ VbT,
                                                 u16* __restrict__ Ob) {
  // regions kept at 64*72 so the whole block (36,864B) is reusable by the
  // O-epilogue transpose; K/V buffers use the first 64*64 of each region.
  __shared__ alignas(16) u16 smem[4][64 * 72];
  const int b = blockIdx.x >> 4, h = blockIdx.x & 15;
  const int q0 = blockIdx.y * 256;
  const int t = threadIdx.x;
  const int wave = t >> 6, lane = t & 63, quad = lane >> 4, l16 = lane & 15;
  const int sw = l16 & 7;

  // Q fragments (pre-scaled)
  bf16x8 aq[4][2];
#pragma unroll
  for (int qf = 0; qf < 4; qf++)
#pragma unroll
    for (int c = 0; c < 2; c++)
      aq[qf][c] = *(const bf16x8*)&Qb[(size_t)(b * 2048 + q0 + wave * 64 + qf * 16 + l16) * 1024 +
                                      h * 64 + c * 32 + quad * 8];

  f32x4 Oacc[4][4] = {};   // [qf][dh-frag g]; C-layout col=q, row=dh_local
  float psum[4] = {};      // per-lane partial row sum for q=l16 (per qf)

  const u16* kBase = Kb + (size_t)(b * 2048) * 1024 + h * 64;
  const u16* vBase = VbT + (size_t)((b * 16 + h) * 64) * 2048;

  // staging: slot s = i*256 + t covers (row r = s>>3, granule gslot = s&7);
  // source granule = gslot ^ (r&7); LDS dest linear = s*16B (base wave-uniform).
  const int sRow0 = t >> 3, sG0 = (t & 7) ^ (sRow0 & 7);          // i=0
  const int sRow1 = (256 + t) >> 3, sG1 = (t & 7) ^ (sRow1 & 7);  // i=1

  auto STAGE = [&](int kt, int p) {
    const int kv = kt * 64;
    u16* Kls = smem[p];
    u16* Vls = smem[2 + p];
    gld16(kBase + (size_t)(kv + sRow0) * 1024 + sG0 * 8, &Kls[(wave * 64) * 8]);
    gld16(kBase + (size_t)(kv + sRow1) * 1024 + sG1 * 8, &Kls[(256 + wave * 64) * 8]);
    gld16(vBase + (size_t)sRow0 * 2048 + kv + sG0 * 8, &Vls[(wave * 64) * 8]);
    gld16(vBase + (size_t)sRow1 * 2048 + kv + sG1 * 8, &Vls[(256 + wave * 64) * 8]);
  };

  STAGE(0, 0);
  QDRAIN();
  QBAR();

  for (int kt = 0; kt < 32; kt++) {
    const int p = kt & 1;
    u16* Kls = smem[p];
    u16* Vls = smem[2 + p];
    if (kt < 31) STAGE(kt + 1, p ^ 1);   // flies across this iter's compute

    // S^T = K Q^T : A = K-frag (m=kv), B = Q-frag (n=q)
    f32x4 st[4][4];   // [qf][kv-frag f]
#pragma unroll
    for (int qf = 0; qf < 4; qf++)
#pragma unroll
      for (int f = 0; f < 4; f++) st[qf][f] = f32x4{0.f, 0.f, 0.f, 0.f};
#pragma unroll
    for (int c = 0; c < 2; c++) {
      bf16x8 bk[4];
#pragma unroll
      for (int f = 0; f < 4; f++)
        bk[f] = *(const bf16x8*)&Kls[(f * 16 + l16) * 64 + ((c * 4 + quad) ^ sw) * 8];
#pragma unroll
      for (int qf = 0; qf < 4; qf++)
#pragma unroll
        for (int f = 0; f < 4; f++)
          st[qf][f] = __builtin_amdgcn_mfma_f32_16x16x32_bf16(bk[f], aq[qf][c], st[qf][f], 0, 0, 0);
    }

    // V A-operand frags (K=32: k = quad*8+j within each 32-kv chunk), shared by all qf
    f16x8 va[2][4];  // [kf=kv32-chunk][g=dh-frag]
#pragma unroll
    for (int kf = 0; kf < 2; kf++)
#pragma unroll
      for (int g = 0; g < 4; g++)
        va[kf][g] = *(const f16x8*)&Vls[(g * 16 + l16) * 64 + ((kf * 4 + quad) ^ sw) * 8];

    // p~ = 2^s, packed f16; accumulate row sums; P -> B-frags via permlane swaps
#pragma unroll
    for (int qf = 0; qf < 4; qf++) {
      union PK { hf16x2 r; f16x2 v; __half2 h; unsigned int u; };
      PK e01[4], e23[4];
      __half2 it2 = __half2{__half(0.f), __half(0.f)};
#pragma unroll
      for (int f = 0; f < 4; f++) {
        PK a01, a23;
        a01.r = __builtin_amdgcn_cvt_pkrtz(st[qf][f][0], st[qf][f][1]);
        a23.r = __builtin_amdgcn_cvt_pkrtz(st[qf][f][2], st[qf][f][3]);
        e01[f].h = h2exp2(a01.h);
        e23[f].h = h2exp2(a23.h);
        it2 = __hadd2(it2, __hadd2(e01[f].h, e23[f].h));
      }
      psum[qf] += __low2float(it2) + __high2float(it2);
      // in-register C->B redistribution (rows 8*qd+{0..7} per chunk kf)
#pragma unroll
      for (int kf = 0; kf < 2; kf++) {
        u32x2 sa = __builtin_amdgcn_permlane32_swap(e01[2 * kf].u, e01[2 * kf + 1].u, false, false);
        u32x2 sb = __builtin_amdgcn_permlane32_swap(e23[2 * kf].u, e23[2 * kf + 1].u, false, false);
        u32x2 ta = __builtin_amdgcn_permlane16_swap(sa[0], sa[1], false, false);
        u32x2 tb = __builtin_amdgcn_permlane16_swap(sb[0], sb[1], false, false);
        union { unsigned int u[4]; f16x8 v; } pb;
        pb.u[0] = ta[0];  // rows 8qd+{0,1}
        pb.u[1] = tb[0];  // rows 8qd+{2,3}
        pb.u[2] = ta[1];  // rows 8qd+{4,5}
        pb.u[3] = tb[1];  // rows 8qd+{6,7}
#pragma unroll
        for (int g = 0; g < 4; g++)
          Oacc[qf][g] = __builtin_amdgcn_mfma_f32_16x16x32_f16(va[kf][g], pb.v, Oacc[qf][g], 0, 0, 0);
      }
    }

    QDRAIN();   // next tile's 4 gld16 per thread: issued an iteration ago, L2-warm
    QBAR();
  }

  // psum: lanes with same l16 across the 4 quads hold disjoint kv subsets
  float inv[4];
#pragma unroll
  for (int qf = 0; qf < 4; qf++) {
    float v = psum[qf];
    v += __shfl_xor(v, 16);
    v += __shfl_xor(v, 32);
    inv[qf] = 1.f / v;
  }

  // epilogue: O^T (col=q, row=dh) -> LDS transpose -> coalesced row-major store
  // (loop ended with a barrier; whole 36,864B smem block is reusable)
  u16* Ols = (u16*)smem;  // 256 rows x 72 pitch = 18432 u16 (fits exactly)
#pragma unroll
  for (int qf = 0; qf < 4; qf++)
#pragma unroll
    for (int g = 0; g < 4; g++) {
      u16x4 o;
#pragma unroll
      for (int r = 0; r < 4; r++) o[r] = f2bf(Oacc[qf][g][r] * inv[qf]);
      *(u16x4*)&Ols[(wave * 64 + qf * 16 + l16) * 72 + g * 16 + quad * 4] = o;
    }
  __syncthreads();
  u16* gO = Ob + (size_t)(b * 2048 + q0 + t) * 1024 + h * 64;
#pragma unroll
  for (int j = 0; j < 8; j++)
    *(u16x8*)(gO + j * 8) = *(const u16x8*)&Ols[t * 72 + j * 8];
}

// ---------------- LayerNorm (bf16 input, fp32 output) ----------------

__global__ __launch_bounds__(256) void k_ln(const u16* __restrict__ y,
                                            const float* __restrict__ g,
                                            const float* __restrict__ bt,
                                            float* __restrict__ out) {
  const int row = blockIdx.x;
  const int t = threadIdx.x;
  u16x4 rv = *(const u16x4*)(y + row * 1024 + t * 4);
  float vx = bf2f(rv[0]), vy = bf2f(rv[1]), vz = bf2f(rv[2]), vw = bf2f(rv[3]);
  float s1 = vx + vy + vz + vw;
  float s2 = vx * vx + vy * vy + vz * vz + vw * vw;
#pragma unroll
  for (int off = 32; off; off >>= 1) {
    s1 += __shfl_down(s1, off);
    s2 += __shfl_down(s2, off);
  }
  __shared__ float red[10];
  const int wave = t >> 6, lane = t & 63;
  if (lane == 0) { red[wave] = s1; red[4 + wave] = s2; }
  __syncthreads();
  if (t == 0) {
    float a = red[0] + red[1] + red[2] + red[3];
    float bsum = red[4] + red[5] + red[6] + red[7];
    float mean = a * (1.f / 1024.f);
    float var = bsum * (1.f / 1024.f) - mean * mean;
    red[8] = mean;
    red[9] = rsqrtf(var + 1e-6f);
  }
  __syncthreads();
  float mean = red[8], iv = red[9];
  float4 gv = *(const float4*)(g + t * 4);
  float4 bv = *(const float4*)(bt + t * 4);
  float4 o;
  o.x = (vx - mean) * iv * gv.x + bv.x;
  o.y = (vy - mean) * iv * gv.y + bv.y;
  o.z = (vz - mean) * iv * gv.z + bv.z;
  o.w = (vw - mean) * iv * gv.w + bv.w;
  *(float4*)(out + row * 1024 + t * 4) = o;
}

// ---------------- launch ----------------

extern "C" void kernel_launch(void* const* d_in, const int* in_sizes, int n_in,
                              void* d_out, int out_size, void* d_ws, size_t ws_size,
                              hipStream_t stream) {
  const float* x  = (const float*)d_in[0];
  const float* wq = (const float*)d_in[1];
  const float* wk = (const float*)d_in[2];
  const float* wv = (const float*)d_in[3];
  const float* wp = (const float*)d_in[4];
  const float* bp = (const float*)d_in[5];
  const float* g  = (const float*)d_in[6];
  const float* bt = (const float*)d_in[7];
  float* out = (float*)d_out;
  char* ws = (char*)d_ws;

  u16* xbf = (u16*)(ws);
  u16* wqT = (u16*)(ws + (16 << 20));        // [3072][1024] fused: wq|wk|wv
  u16* wkT = wqT + (size_t)1024 * 1024;
  u16* wvT = wqT + (size_t)2048 * 1024;
  u16* wpT = (u16*)(ws + (22 << 20));
  u16* Qb  = (u16*)(ws + (24 << 20));
  u16* Kb  = (u16*)(ws + (40 << 20));
  u16* VbT = (u16*)(ws + (56 << 20));
  u16* Ob  = (u16*)(ws);                   // aliases xbf (dead after QKV GEMM)
  u16* ypre = (u16*)(ws + (24 << 20));     // bf16, aliases Qb (dead after attention)

  k_convx<<<4096, 256, 0, stream>>>(x, xbf);
  k_convwT<<<dim3(16, 16, 4), 256, 0, stream>>>(wq, wk, wv, wp, wqT, wkT, wvT, wpT);
  k_gemm_qkv<<<dim3(64, 24), 256, 0, stream>>>(xbf, wqT, Qb, Kb, VbT);
  k_attn<<<dim3(64, 8), 256, 0, stream>>>(Qb, Kb, VbT, Ob);
  k_gemm_proj<<<dim3(64, 8), 256, 0, stream>>>(Ob, wpT, x, bp, ypre);
  k_ln<<<8192, 256, 0, stream>>>(ypre, g, bt, out);
}